// Round 9
// baseline (261.133 us; speedup 1.0000x reference)
//
#include <hip/hip_runtime.h>
#include <cstdint>
#include <cstddef>

typedef int int4v __attribute__((ext_vector_type(4)));
typedef signed char schar;

#define DEVI __device__ __forceinline__

DEVI void load_lds16(const void* g, void* l) {
  __builtin_amdgcn_global_load_lds(
      (const __attribute__((address_space(1))) void*)g,
      (__attribute__((address_space(3))) void*)l, 16, 0, 0);
}

// Bare advisory waits — no sched_barrier, no memory clobber.
#define BAR() __builtin_amdgcn_s_barrier()
#define LGKM(n) asm volatile("s_waitcnt lgkmcnt(" #n ")")
#define VMW(n) asm volatile("s_waitcnt vmcnt(" #n ")")

// ---- pack int32 -> int8, linear (4 elems/thread) ----
__global__ __launch_bounds__(256) void pack_i8(const int* __restrict__ src,
                                               signed char* __restrict__ dst,
                                               int n4) {
  int i = blockIdx.x * 256 + threadIdx.x;
  if (i >= n4) return;
  int4v v = ((const int4v*)src)[i];
  int p = (v.x & 255) | ((v.y & 255) << 8) | ((v.z & 255) << 16) | (v.w << 24);
  ((int*)dst)[i] = p;
}

// ---- pack + transpose: w[K][N] int32 -> wT[N][K] int8, 64x64 LDS tiles ----
__global__ __launch_bounds__(256) void pack_wT(const int* __restrict__ w,
                                               signed char* __restrict__ wT,
                                               int K, int N) {
  __shared__ signed char t[64][68];
  int n0 = blockIdx.x * 64, k0 = blockIdx.y * 64;
  int tr = threadIdx.x >> 6, tc = threadIdx.x & 63;
#pragma unroll
  for (int i = 0; i < 16; ++i) {
    int r = i * 4 + tr;
    t[r][tc] = (signed char)w[(size_t)(k0 + r) * N + n0 + tc];
  }
  __syncthreads();
#pragma unroll
  for (int i = 0; i < 16; ++i) {
    int r = i * 4 + tr;
    wT[(size_t)(n0 + r) * K + k0 + tc] = t[tc][r];
  }
}

// ---- 256x256 i8 GEMM, B DIRECT-FROM-GLOBAL: C = A[M,K] * BT[N,K]^T ----
// 8 waves (2Mx4N), 128x64 out/wave, acc[8][4] = 128 AGPR.
// BK=64 B (one 16x16x64 K-step per tile).
// A: LDS-staged 2 tiles ahead, 4 buffers x 16 KB (64 KiB LDS total).
// B: each wave loads its 4 B-frags DIRECTLY global->VGPR (16 B/lane,
//    exact bytes, L2-resident 4 MB panel). Removes 1/3 of LDS-port reads,
//    half the staging writes, half the vmcnt traffic. Compiler inserts
//    its own counted vmcnt for the B->MFMA dependency (leaves A-staging
//    in flight).
// Sync per tile: lgkm(0) (A-read WAR) + vmcnt(2) (A-stage discipline,
// never 0 mid-loop) + 1 barrier.
template <int EPI>
__global__ __launch_bounds__(512, 2) void gemmD(
    const schar* __restrict__ A, const schar* __restrict__ BT,
    int M, int N, int K, const int* __restrict__ bias_i,
    const float* __restrict__ alphaP, const float* __restrict__ betaP,
    const float* __restrict__ bias_f, schar* __restrict__ outQ,
    float* __restrict__ outF) {
  extern __shared__ schar lds[];

  const int tid = threadIdx.x;
  const int wid = tid >> 6, lane = tid & 63;
  const int wr = wid >> 2, wc = wid & 3;  // 2M x 4N waves
  const int l16 = lane & 15, l4 = lane >> 4;

  // XCD-bijective block swizzle (nwg % 8 == 0 for both GEMMs)
  const int gx = gridDim.x;
  const int nwg = gx * gridDim.y;
  const int bid = blockIdx.y * gx + blockIdx.x;
  const int swz = (bid & 7) * (nwg >> 3) + (bid >> 3);
  const int rowBase = (swz / gx) * 256;
  const int colBase = (swz % gx) * 256;
  const int NT = K >> 6;  // 64-B K-tiles

  // pin scalar params; drain SMEM
  const float alpha = alphaP[0];
  const float beta = (EPI == 0) ? betaP[0] : 0.f;
  asm volatile("" ::"s"(alpha), "s"(beta));
  LGKM(0);

  // A staging sources (pre-swizzled global slot; LDS dest linear)
  const schar* gA[2];
#pragma unroll
  for (int c = 0; c < 2; ++c) {
    int o = c * 8192 + tid * 16;
    int r = o >> 6;  // row 0..255 (64-B rows)
    int g = ((o >> 4) & 3) ^ ((r >> 1) & 3);
    gA[c] = A + (size_t)(rowBase + r) * K + g * 16;
  }
  auto stageA = [&](int buf, int t) {
    schar* d = lds + buf * 16384 + wid * 1024;
    load_lds16(gA[0] + (size_t)t * 64, d);
    load_lds16(gA[1] + (size_t)t * 64, d + 8192);
  };

  // B direct-gather pointers: lane reads BT[col][T*64 + l4*16 .. +15]
  const schar* gBp[4];
#pragma unroll
  for (int ni = 0; ni < 4; ++ni)
    gBp[ni] =
        BT + (size_t)(colBase + wc * 64 + ni * 16 + l16) * K + l4 * 16;

  // A fragment read offset: slot = l4 ^ ((l16>>1)&3) (row-base mult of 16)
  const int slotc = (l4 ^ ((l16 >> 1) & 3)) * 16 + l16 * 64;
  const int aoff = wr * 8192 + slotc;  // + f*1024, f=0..7

  int4v acc[8][4] = {};

  // prologue: stage A tiles 0,1; drain; barrier
  stageA(0, 0);
  stageA(1, 1);
  VMW(0);
  BAR();

  for (int T = 0; T < NT; ++T) {
    const schar* Ab = lds + (T & 3) * 16384;

    // B frags direct from global (compiler-tracked counted vmcnt)
    int4v bF[4];
#pragma unroll
    for (int ni = 0; ni < 4; ++ni)
      bF[ni] = *(const int4v*)(gBp[ni] + (size_t)T * 64);

    // stage A two tiles ahead
    if (T + 2 < NT) stageA((T + 2) & 3, T + 2);

    // A frags from LDS
    int4v aF[8];
#pragma unroll
    for (int f = 0; f < 8; ++f)
      aF[f] = *(const int4v*)(Ab + aoff + f * 1024);

    __builtin_amdgcn_s_setprio(1);
#pragma unroll
    for (int mi = 0; mi < 8; ++mi)
#pragma unroll
      for (int ni = 0; ni < 4; ++ni)
        acc[mi][ni] = __builtin_amdgcn_mfma_i32_16x16x64_i8(
            aF[mi], bF[ni], acc[mi][ni], 0, 0, 0);
    __builtin_amdgcn_s_setprio(0);

    LGKM(0);  // A-reads of buf (T&3) drained before barrier (WAR)
    if (T + 2 < NT) {
      VMW(2);  // A-stage(T+1) retired; A-stage(T+2) stays in flight
    } else {
      VMW(0);  // tail drain
    }
    BAR();
  }

  // ---- epilogue; C/D frag: col = lane&15, row = (lane>>4)*4 + j ----
  if (EPI == 0) {
#pragma unroll
    for (int MI = 0; MI < 8; ++MI) {
      int row = rowBase + wr * 128 + MI * 16 + l4 * 4;
#pragma unroll
      for (int NI = 0; NI < 4; ++NI) {
        int col = colBase + wc * 64 + NI * 16 + l16;
        float bt = (float)bias_i[col] * beta;
#pragma unroll
        for (int j = 0; j < 4; ++j) {
          float h = (float)acc[MI][NI][j] * alpha + bt;
          h = fmaxf(h, 0.f);
          h = rintf(h);  // numpy round-half-even
          h = fminf(h, 127.f);
          outQ[(size_t)(row + j) * N + col] = (schar)h;
        }
      }
    }
  } else {
#pragma unroll
    for (int MI = 0; MI < 8; ++MI) {
      int row = rowBase + wr * 128 + MI * 16 + l4 * 4;
#pragma unroll
      for (int NI = 0; NI < 4; ++NI) {
        int col = colBase + wc * 64 + NI * 16 + l16;
        float bv = bias_f[col];
#pragma unroll
        for (int j = 0; j < 4; ++j)
          outF[(size_t)(row + j) * N + col] =
              (float)acc[MI][NI][j] * alpha + bv;
      }
    }
  }
}

extern "C" void kernel_launch(void* const* d_in, const int* in_sizes, int n_in,
                              void* d_out, int out_size, void* d_ws,
                              size_t ws_size, hipStream_t stream) {
  const int M = 16384, H = 1024, I = 4096;  // B*S = 16384
  const int* hidden = (const int*)d_in[0];
  const int* w_fc = (const int*)d_in[1];
  const int* b_fc = (const int*)d_in[2];
  const float* alpha_fc = (const float*)d_in[3];
  const float* beta_fc = (const float*)d_in[4];
  const int* w_proj = (const int*)d_in[5];
  const float* b_proj = (const float*)d_in[6];
  const float* alpha_proj = (const float*)d_in[7];
  float* out = (float*)d_out;

  signed char* hq = (signed char*)d_ws;     // [M][I]  64 MB
  signed char* aP = hq + (size_t)M * I;     // [M][H]  16 MB
  signed char* wfcT = aP + (size_t)M * H;   // [I][H]   4 MB (w_fc^T)
  signed char* wpT = wfcT + (size_t)I * H;  // [H][I]   4 MB (w_proj^T)

  hipFuncSetAttribute((const void*)gemmD<0>,
                      hipFuncAttributeMaxDynamicSharedMemorySize, 65536);
  hipFuncSetAttribute((const void*)gemmD<1>,
                      hipFuncAttributeMaxDynamicSharedMemorySize, 65536);

  pack_i8<<<(M * H / 4 + 255) / 256, 256, 0, stream>>>(hidden, aP, M * H / 4);
  pack_wT<<<dim3(I / 64, H / 64), 256, 0, stream>>>(w_fc, wfcT, H, I);
  pack_wT<<<dim3(H / 64, I / 64), 256, 0, stream>>>(w_proj, wpT, I, H);

  gemmD<0><<<dim3(I / 256, M / 256), 512, 65536, stream>>>(
      aP, wfcT, M, I, H, b_fc, alpha_fc, beta_fc, nullptr, hq, nullptr);
  gemmD<1><<<dim3(H / 256, M / 256), 512, 65536, stream>>>(
      hq, wpT, M, H, I, nullptr, alpha_proj, nullptr, b_proj, nullptr, out);
}

// Round 10
// 173.443 us; speedup vs baseline: 1.5056x; 1.5056x over previous
//
#include <hip/hip_runtime.h>
#include <cstdint>
#include <cstddef>

typedef int int4v __attribute__((ext_vector_type(4)));
typedef signed char schar;

#define DEVI __device__ __forceinline__

DEVI void load_lds16(const void* g, void* l) {
  __builtin_amdgcn_global_load_lds(
      (const __attribute__((address_space(1))) void*)g,
      (__attribute__((address_space(3))) void*)l, 16, 0, 0);
}

// Bare advisory waits — no sched_barrier, no memory clobber.
#define BAR() __builtin_amdgcn_s_barrier()
#define LGKM(n) asm volatile("s_waitcnt lgkmcnt(" #n ")")
#define VMW(n) asm volatile("s_waitcnt vmcnt(" #n ")")

// ---- pack int32 -> int8, linear (4 elems/thread) ----
__global__ __launch_bounds__(256) void pack_i8(const int* __restrict__ src,
                                               signed char* __restrict__ dst,
                                               int n4) {
  int i = blockIdx.x * 256 + threadIdx.x;
  if (i >= n4) return;
  int4v v = ((const int4v*)src)[i];
  int p = (v.x & 255) | ((v.y & 255) << 8) | ((v.z & 255) << 16) | (v.w << 24);
  ((int*)dst)[i] = p;
}

// ---- pack + transpose: w[K][N] int32 -> wT[N][K] int8, 64x64 LDS tiles ----
__global__ __launch_bounds__(256) void pack_wT(const int* __restrict__ w,
                                               signed char* __restrict__ wT,
                                               int K, int N) {
  __shared__ signed char t[64][68];
  int n0 = blockIdx.x * 64, k0 = blockIdx.y * 64;
  int tr = threadIdx.x >> 6, tc = threadIdx.x & 63;
#pragma unroll
  for (int i = 0; i < 16; ++i) {
    int r = i * 4 + tr;
    t[r][tc] = (signed char)w[(size_t)(k0 + r) * N + n0 + tc];
  }
  __syncthreads();
#pragma unroll
  for (int i = 0; i < 16; ++i) {
    int r = i * 4 + tr;
    wT[(size_t)(n0 + r) * K + k0 + tc] = t[tc][r];
  }
}

// ---- 256x256 16-wave i8 GEMM: C[M,N] = A[M,K] * BT[N,K]^T ----
// 1024 threads = 16 waves (4Mx4N), wave-tile 64x64, acc[4][4] = 64 AGPR,
// ~110 total regs/wave -> 4 WAVES/SIMD resident. Latency hiding is
// TLP-driven (schedule-insensitive): while one wave drains its 8-read
// group, 3 others feed the matrix pipe. (R2-R9: 2 waves/SIMD lockstep
// serialized port drain vs MFMA at every schedule tried.)
// BK=128 B (2 K-steps of 16x16x64); LDS A[2][256][128]+B[2][256][128]
// = 128 KiB; stage T+1 early, vmcnt(0)+barrier per tile (R5 discipline).
template <int EPI>
__global__ __launch_bounds__(1024, 1) void gemmT(
    const schar* __restrict__ A, const schar* __restrict__ BT,
    int M, int N, int K, const int* __restrict__ bias_i,
    const float* __restrict__ alphaP, const float* __restrict__ betaP,
    const float* __restrict__ bias_f, schar* __restrict__ outQ,
    float* __restrict__ outF) {
  extern __shared__ schar lds[];

  const int tid = threadIdx.x;
  const int wid = tid >> 6, lane = tid & 63;
  const int wr = wid >> 2, wc = wid & 3;  // 4M x 4N waves, 64x64 each
  const int l16 = lane & 15, l4 = lane >> 4;

  // XCD-bijective block swizzle (nwg % 8 == 0 for both GEMMs)
  const int gx = gridDim.x;
  const int nwg = gx * gridDim.y;
  const int bid = blockIdx.y * gx + blockIdx.x;
  const int swz = (bid & 7) * (nwg >> 3) + (bid >> 3);
  const int rowBase = (swz / gx) * 256;
  const int colBase = (swz % gx) * 256;
  const int NT = K >> 7;  // 128-B K-tiles

  // pin scalar params; drain SMEM
  const float alpha = alphaP[0];
  const float beta = (EPI == 0) ? betaP[0] : 0.f;
  asm volatile("" ::"s"(alpha), "s"(beta));
  LGKM(0);

  // staging sources (pre-swizzled global slot; LDS dest linear).
  // Thread covers bytes c*16384 + tid*16 of each 32 KB tile (c = 0,1).
  const schar* gA[2];
  const schar* gB[2];
#pragma unroll
  for (int c = 0; c < 2; ++c) {
    int o = c * 16384 + tid * 16;
    int r = o >> 7;  // row 0..255 (128-B rows)
    int g = ((o >> 4) & 7) ^ (r & 7);
    gA[c] = A + (size_t)(rowBase + r) * K + g * 16;
    gB[c] = BT + (size_t)(colBase + r) * K + g * 16;
  }
  auto stage = [&](int buf, int t) {
    schar* dA = lds + buf * 32768 + wid * 1024;
    schar* dB = lds + 65536 + buf * 32768 + wid * 1024;
    load_lds16(gA[0] + (size_t)t * 128, dA);
    load_lds16(gA[1] + (size_t)t * 128, dA + 16384);
    load_lds16(gB[0] + (size_t)t * 128, dB);
    load_lds16(gB[1] + (size_t)t * 128, dB + 16384);
  };

  // fragment read offsets; row&7 == l16&7 -> slot is lane-const
  const int so0 = ((0 + l4) ^ (l16 & 7)) * 16 + l16 * 128;  // k-step 0
  const int so1 = ((4 + l4) ^ (l16 & 7)) * 16 + l16 * 128;  // k-step 1
  const int aoff = wr * 8192;  // + mi*2048
  const int boff = wc * 8192;  // + ni*2048

  int4v acc[4][4] = {};
  int4v aF[4], bF[4];

#define RDA(SO, Ab)                                               \
  _Pragma("unroll") for (int mi = 0; mi < 4; ++mi) aF[mi] =       \
      *(const int4v*)((Ab) + aoff + mi * 2048 + (SO))
#define RDB(SO, Bb)                                               \
  _Pragma("unroll") for (int ni = 0; ni < 4; ++ni) bF[ni] =       \
      *(const int4v*)((Bb) + boff + ni * 2048 + (SO))
#define MMALL()                                                        \
  do {                                                                 \
    __builtin_amdgcn_s_setprio(1);                                     \
    _Pragma("unroll") for (int mi = 0; mi < 4; ++mi)                   \
        _Pragma("unroll") for (int ni = 0; ni < 4; ++ni) acc[mi][ni] = \
        __builtin_amdgcn_mfma_i32_16x16x64_i8(aF[mi], bF[ni],          \
                                              acc[mi][ni], 0, 0, 0);   \
    __builtin_amdgcn_s_setprio(0);                                     \
  } while (0)

  // prologue
  stage(0, 0);
  VMW(0);
  BAR();

  for (int T = 0; T < NT; ++T) {
    const int cb = T & 1;
    const schar* Ab = lds + cb * 32768;
    const schar* Bb = lds + 65536 + cb * 32768;

    if (T + 1 < NT) stage(cb ^ 1, T + 1);  // issue early, drains at tile end

    RDA(so0, Ab);
    RDB(so0, Bb);
    LGKM(0);
    MMALL();
    // k-step 1: reuse frag regs (scoreboard enforces WAR vs k0 MFMAs)
    RDA(so1, Ab);
    RDB(so1, Bb);
    LGKM(0);
    MMALL();

    VMW(0);  // own staging landed (issued ~a full tile earlier)
    BAR();   // publish next buffer; all reads of cb done block-wide
  }

  // ---- epilogue; C/D frag: col = lane&15, row = (lane>>4)*4 + j ----
  if (EPI == 0) {
#pragma unroll
    for (int MI = 0; MI < 4; ++MI) {
      int row = rowBase + wr * 64 + MI * 16 + l4 * 4;
#pragma unroll
      for (int NI = 0; NI < 4; ++NI) {
        int col = colBase + wc * 64 + NI * 16 + l16;
        float bt = (float)bias_i[col] * beta;
#pragma unroll
        for (int j = 0; j < 4; ++j) {
          float h = (float)acc[MI][NI][j] * alpha + bt;
          h = fmaxf(h, 0.f);
          h = rintf(h);  // numpy round-half-even
          h = fminf(h, 127.f);
          outQ[(size_t)(row + j) * N + col] = (schar)h;
        }
      }
    }
  } else {
#pragma unroll
    for (int MI = 0; MI < 4; ++MI) {
      int row = rowBase + wr * 64 + MI * 16 + l4 * 4;
#pragma unroll
      for (int NI = 0; NI < 4; ++NI) {
        int col = colBase + wc * 64 + NI * 16 + l16;
        float bv = bias_f[col];
#pragma unroll
        for (int j = 0; j < 4; ++j)
          outF[(size_t)(row + j) * N + col] =
              (float)acc[MI][NI][j] * alpha + bv;
      }
    }
  }
#undef RDA
#undef RDB
#undef MMALL
}

extern "C" void kernel_launch(void* const* d_in, const int* in_sizes, int n_in,
                              void* d_out, int out_size, void* d_ws,
                              size_t ws_size, hipStream_t stream) {
  const int M = 16384, H = 1024, I = 4096;  // B*S = 16384
  const int* hidden = (const int*)d_in[0];
  const int* w_fc = (const int*)d_in[1];
  const int* b_fc = (const int*)d_in[2];
  const float* alpha_fc = (const float*)d_in[3];
  const float* beta_fc = (const float*)d_in[4];
  const int* w_proj = (const int*)d_in[5];
  const float* b_proj = (const float*)d_in[6];
  const float* alpha_proj = (const float*)d_in[7];
  float* out = (float*)d_out;

  signed char* hq = (signed char*)d_ws;     // [M][I]  64 MB
  signed char* aP = hq + (size_t)M * I;     // [M][H]  16 MB
  signed char* wfcT = aP + (size_t)M * H;   // [I][H]   4 MB (w_fc^T)
  signed char* wpT = wfcT + (size_t)I * H;  // [H][I]   4 MB (w_proj^T)

  hipFuncSetAttribute((const void*)gemmT<0>,
                      hipFuncAttributeMaxDynamicSharedMemorySize, 131072);
  hipFuncSetAttribute((const void*)gemmT<1>,
                      hipFuncAttributeMaxDynamicSharedMemorySize, 131072);

  pack_i8<<<(M * H / 4 + 255) / 256, 256, 0, stream>>>(hidden, aP, M * H / 4);
  pack_wT<<<dim3(I / 64, H / 64), 256, 0, stream>>>(w_fc, wfcT, H, I);
  pack_wT<<<dim3(H / 64, I / 64), 256, 0, stream>>>(w_proj, wpT, I, H);

  gemmT<0><<<dim3(I / 256, M / 256), 1024, 131072, stream>>>(
      aP, wfcT, M, I, H, b_fc, alpha_fc, beta_fc, nullptr, hq, nullptr);
  gemmT<1><<<dim3(H / 256, M / 256), 1024, 131072, stream>>>(
      hq, wpT, M, H, I, nullptr, alpha_proj, nullptr, b_proj, nullptr, out);
}